// Round 16
// baseline (121.320 us; speedup 1.0000x reference)
//
#include <hip/hip_runtime.h>

#define CAP    4608        // loose-candidate capacity (R10-R15 verified: exact
                           // <= 4096, loose margins add <= ~3%). PLUS overflow
                           // -proof fallback: if count > CAP, phase 2 scans all
                           // N points (identity) - truncation is impossible.
#define BIGK   1.0e300
#define IDXINF 0x7fffffff

// one bitonic compare-exchange stage across the 64-lane wave,
// lexicographic key (k asc, n asc)
__device__ __forceinline__ void cmpx(double& k, int& n, int lane, int stride, bool up) {
    double ok = __shfl_xor(k, stride);
    int    on = __shfl_xor(n, stride);
    bool oLess = (ok < k) || (ok == k && on < n);
    bool lower = (lane & stride) == 0;
    bool takeOther = lower ? (up ? oLess : !oLess) : (up ? !oLess : oLess);
    if (takeOther) { k = ok; n = on; }
}

// full 64-element bitonic sort across the wave (asc==true -> ascending)
__device__ __forceinline__ void wave_sort64(double& k, int& n, int lane, bool asc) {
    #pragma unroll
    for (int size = 2; size < 64; size <<= 1) {
        bool up = asc ? ((lane & size) == 0) : ((lane & size) != 0);
        #pragma unroll
        for (int stride = size >> 1; stride > 0; stride >>= 1)
            cmpx(k, n, lane, stride, up);
    }
    #pragma unroll
    for (int stride = 32; stride > 0; stride >>= 1)   // final size-64 pass
        cmpx(k, n, lane, stride, asc);
}

// ---- Kernel 1: selection + grouped_xyz; sel indices -> d_ws (ushort) ----
__global__ __launch_bounds__(256, 8) void select_kernel(
    const float* __restrict__ radius_p,
    const float* __restrict__ hmin_p,
    const float* __restrict__ hmax_p,
    const float* __restrict__ xyz,      // (B, N, 3)
    const float* __restrict__ new_xyz,  // (B, P, 3)
    const float* __restrict__ rot,      // (B, P, 3, 3)
    float* __restrict__ out,            // (B, 3+C, P, S)
    unsigned short* __restrict__ selw)  // (B*P, 32)
{
    const int N = 16384, P = 1024, S = 32, OC = 67;
    const int bp  = blockIdx.x;
    const int b   = bp >> 10;          // P = 1024
    const int p   = bp & (P - 1);
    const int tid = threadIdx.x;
    const int lane = tid & 63;
    const int wv   = tid >> 6;

    __shared__ unsigned short cn[CAP]; // loose candidates (ushort: N fits 16b)
    __shared__ double wr2[256];        // per-wave sorted keys for the merge
    __shared__ int    wn[256];
    __shared__ int    cnt;             // loose count
    __shared__ int    cnt2;            // exact survivor count
    __shared__ int    sel[32];

    if (tid == 0) { cnt = 0; cnt2 = 0; }
    __syncthreads();

    const double radius = (double)radius_p[0];
    const double hmin   = (double)hmin_p[0];
    const double hmax   = (double)hmax_p[0];
    const double rad2   = radius * radius;

    const float* nx = new_xyz + (size_t)bp * 3;
    const double cx = nx[0], cy = nx[1], cz = nx[2];
    const float* rp = rot + (size_t)bp * 9;
    const double r00 = rp[0], r01 = rp[1], r02 = rp[2];
    const double r10 = rp[3], r11 = rp[4], r12 = rp[5];
    const double r20 = rp[6], r21 = rp[7], r22 = rp[8];

    // Projection-form f32 loose filter: local_d = P.u_d - cp_d where
    // cp_d = c.u_d is folded into one constant per output dim -> no per-point
    // subtractions. Error: abs err <= ~1e-5, 50-100x under the margins.
    const float r00f = (float)r00, r01f = (float)r01, r02f = (float)r02;
    const float r10f = (float)r10, r11f = (float)r11, r12f = (float)r12;
    const float r20f = (float)r20, r21f = (float)r21, r22f = (float)r22;
    const float cpxf = (float)(cx * r00 + cy * r10 + cz * r20);
    const float cpyf = (float)(cx * r01 + cy * r11 + cz * r21);
    const float cpzf = (float)(cx * r02 + cy * r12 + cz * r22);
    const float hminf = (float)hmin - 5.0e-4f;
    const float hmaxf = (float)hmax + 5.0e-4f;
    const float rad2f = (float)rad2 + 1.0e-3f;

    const float* xb = xyz + (size_t)b * N * 3;
    const float4* vp = reinterpret_cast<const float4*>(xb);

    // ---- Phase 1: pure-f32 loose scan, software-pipelined loads,
    //      wave-aggregated candidate append (1 LDS atomic per wave-group
    //      instead of ~330 serialized per-lane atomics per block) ----
    float4 a0 = vp[tid * 3 + 0], a1 = vp[tid * 3 + 1], a2 = vp[tid * 3 + 2];
    for (int it = 0; it < 16; ++it) {               // 16 * 1024 = N
        const float4* q = vp + ((it + 1) & 15) * 768 + tid * 3;
        float4 b0 = q[0], b1 = q[1], b2 = q[2];     // prefetch (issue-early)
        int g = it * 1024 + tid * 4;
        float px[4], py[4], pz[4];
        px[0]=a0.x; py[0]=a0.y; pz[0]=a0.z;
        px[1]=a0.w; py[1]=a1.x; pz[1]=a1.y;
        px[2]=a1.z; py[2]=a1.w; pz[2]=a2.x;
        px[3]=a2.y; py[3]=a2.z; pz[3]=a2.w;
        #pragma unroll
        for (int k = 0; k < 4; ++k) {
            float xf  = fmaf(px[k], r00f, fmaf(py[k], r10f, fmaf(pz[k], r20f, -cpxf)));
            float yf  = fmaf(px[k], r01f, fmaf(py[k], r11f, fmaf(pz[k], r21f, -cpyf)));
            float zf  = fmaf(px[k], r02f, fmaf(py[k], r12f, fmaf(pz[k], r22f, -cpzf)));
            float r2f = fmaf(yf, yf, zf * zf);
            bool pass = (xf >= hminf && xf <= hmaxf && r2f < rad2f);
            unsigned long long bal = __ballot(pass);
            if (bal) {                               // wave-uniform branch
                int base = 0;
                if (lane == 0) base = atomicAdd(&cnt, __popcll(bal));
                base = __shfl(base, 0);
                if (pass) {
                    int pos = base + __popcll(bal & ((1ull << lane) - 1ull));
                    if (pos < CAP) cn[pos] = (unsigned short)(g + k);
                }
            }
        }
        a0 = b0; a1 = b1; a2 = b2;
    }
    __syncthreads();

    // Overflow-proof: if loose set overflowed, scan ALL points in phase 2.
    int  Mloose = cnt;
    bool ident  = false;
    if (Mloose > CAP) { Mloose = N; ident = true; }

    // ---- Phase 2: exact f64 decision fused into chunk load + streaming
    //      bitonic top-64 per wave, then 4-way merge ----
    // Exact decision (same op order as verified R1-R15) once per candidate,
    // dense 64-wide chunks; rejects = BIGK sentinels; survivor count via
    // ballot popcount. Order-independent -> append order irrelevant.
    double rk = BIGK; int rn = IDXINF;
    int msum = 0;
    const int nch = (Mloose + 63) >> 6;
    for (int ch = wv; ch < nch; ch += 4) {
        int j = (ch << 6) + lane;
        double ck = BIGK; int cnn = IDXINF;
        bool ok = false;
        if (j < Mloose) {
            int n = ident ? j : (int)cn[j];
            double dx = (double)xb[n * 3 + 0] - cx;
            double dy = (double)xb[n * 3 + 1] - cy;
            double dz = (double)xb[n * 3 + 2] - cz;
            double x = dx * r00 + dy * r10 + dz * r20;
            double y = dx * r01 + dy * r11 + dz * r21;
            double z = dx * r02 + dy * r12 + dz * r22;
            double r2 = y * y + z * z;
            if (x >= hmin && x <= hmax && r2 < rad2) { ok = true; ck = r2; cnn = n; }
        }
        msum += __popcll(__ballot(ok));             // wave-uniform count
        wave_sort64(ck, cnn, lane, false);          // chunk descending
        if ((ck < rk) || (ck == rk && cnn < rn)) { rk = ck; rn = cnn; }  // keep 64 smallest
        #pragma unroll
        for (int stride = 32; stride > 0; stride >>= 1)  // bitonic clean -> ascending
            cmpx(rk, rn, lane, stride, true);
    }
    if (lane == 0 && msum > 0) atomicAdd(&cnt2, msum);
    // park each wave's sorted list for the cross-wave merge
    wr2[(wv << 6) + lane] = rk;
    wn [(wv << 6) + lane] = rn;
    __syncthreads();

    if (wv == 0) {
        const int Mtrue = cnt2;
        #pragma unroll
        for (int w = 1; w < 4; ++w) {
            int src = (w << 6) + (63 - lane);       // reversed -> descending
            double ck = wr2[src]; int cnn = wn[src];
            if ((ck < rk) || (ck == rk && cnn < rn)) { rk = ck; rn = cnn; }
            #pragma unroll
            for (int stride = 32; stride > 0; stride >>= 1)
                cmpx(rk, rn, lane, stride, true);
        }
        // lanes 0..31 now hold the exact top-32 in ascending (r2, idx) order
        int nsel  = min(Mtrue, S);
        int first = __shfl(rn, 0);
        int v = (lane < nsel) ? rn : ((nsel > 0) ? first : 0);
        if (lane < S) sel[lane] = v;
    }
    __syncthreads();

    // ---- grouped_xyz + sel store ----
    if (tid < S) {
        int n = sel[tid];
        selw[(size_t)bp * S + tid] = (unsigned short)n;
        double dx = (double)xb[n * 3 + 0] - cx;
        double dy = (double)xb[n * 3 + 1] - cy;
        double dz = (double)xb[n * 3 + 2] - cz;
        float x = (float)(dx * r00 + dy * r10 + dz * r20);
        float y = (float)(dx * r01 + dy * r11 + dz * r21);
        float z = (float)(dx * r02 + dy * r12 + dz * r22);
        float* o = out + (((size_t)b * OC + 0) * P + p) * S + tid;
        o[0 * (size_t)P * S] = x;
        o[1 * (size_t)P * S] = y;
        o[2 * (size_t)P * S] = z;
    }
}

// ---- Kernel 2: transposed feature gather, one feat row per block ----
// grid 512, block 1024 (R9 mapping, 4x the waves/CU): c = bid & 63,
// half = (bid>>6) & 1, b = bid >> 7. Each thread does 16 INDEPENDENT
// gathers (load-all-then-store-all -> 16 outstanding loads of MLP).
// Nontemporal stores keep the 33.5 MB output stream from evicting the
// L2-hot feat rows.
__global__ __launch_bounds__(1024, 8) void gather_kernel(
    const float* __restrict__ feat,           // (B, C, N)
    const unsigned short* __restrict__ selw,  // (B*P, 32)
    float* __restrict__ out)                  // (B, 3+C, P, S)
{
    const int N = 16384, P = 1024, C = 64, S = 32, OC = 67;
    const int bid  = blockIdx.x;
    const int c    = bid & 63;
    const int half = (bid >> 6) & 1;
    const int b    = bid >> 7;
    const int tid  = threadIdx.x;

    __shared__ unsigned short st[512 * 32];   // 32 KB sel tile (512 queries)

    const uint4* sp = reinterpret_cast<const uint4*>(
        selw + ((size_t)b * P + half * 512) * S);
    uint4* dl = reinterpret_cast<uint4*>(st);
    dl[tid]        = sp[tid];                 // 2048 uint4 / 1024 thr
    dl[1024 + tid] = sp[1024 + tid];
    __syncthreads();

    const float* fr = feat + ((size_t)b * C + c) * N;
    float* ob = out + (((size_t)b * OC + 3 + c) * P + half * 512) * S;

    int   ix[16];
    float v [16];
    #pragma unroll
    for (int k = 0; k < 16; ++k)              // LDS reads (cheap)
        ix[k] = st[k * 1024 + tid];
    #pragma unroll
    for (int k = 0; k < 16; ++k)              // 16 outstanding global loads
        v[k] = fr[ix[k]];
    #pragma unroll
    for (int k = 0; k < 16; ++k)              // coalesced streaming stores
        __builtin_nontemporal_store(v[k], &ob[k * 1024 + tid]);
}

extern "C" void kernel_launch(void* const* d_in, const int* in_sizes, int n_in,
                              void* d_out, int out_size, void* d_ws, size_t ws_size,
                              hipStream_t stream) {
    const float* radius  = (const float*)d_in[0];
    const float* hmin    = (const float*)d_in[1];
    const float* hmax    = (const float*)d_in[2];
    // d_in[3] = nsample (int, fixed 32) — compile-time constant here
    const float* xyz     = (const float*)d_in[4];
    const float* new_xyz = (const float*)d_in[5];
    const float* rot     = (const float*)d_in[6];
    const float* feat    = (const float*)d_in[7];
    float* out = (float*)d_out;
    unsigned short* selw = (unsigned short*)d_ws;   // 4096*32*2 = 256 KB

    hipLaunchKernelGGL(select_kernel, dim3(4096), dim3(256), 0, stream,
                       radius, hmin, hmax, xyz, new_xyz, rot, out, selw);
    hipLaunchKernelGGL(gather_kernel, dim3(512), dim3(1024), 0, stream,
                       feat, selw, out);
}

// Round 17
// 108.810 us; speedup vs baseline: 1.1150x; 1.1150x over previous
//
#include <hip/hip_runtime.h>

#define CAP    4608        // loose-candidate capacity (R10-R15 verified: exact
                           // <= 4096, loose margins add <= ~3%). PLUS overflow
                           // -proof fallback: if count > CAP, phase 2 scans all
                           // N points (identity) - truncation is impossible.
#define BIGK   1.0e300
#define IDXINF 0x7fffffff

// one bitonic compare-exchange stage across the 64-lane wave,
// lexicographic key (k asc, n asc)
__device__ __forceinline__ void cmpx(double& k, int& n, int lane, int stride, bool up) {
    double ok = __shfl_xor(k, stride);
    int    on = __shfl_xor(n, stride);
    bool oLess = (ok < k) || (ok == k && on < n);
    bool lower = (lane & stride) == 0;
    bool takeOther = lower ? (up ? oLess : !oLess) : (up ? !oLess : oLess);
    if (takeOther) { k = ok; n = on; }
}

// full 64-element bitonic sort across the wave (asc==true -> ascending)
__device__ __forceinline__ void wave_sort64(double& k, int& n, int lane, bool asc) {
    #pragma unroll
    for (int size = 2; size < 64; size <<= 1) {
        bool up = asc ? ((lane & size) == 0) : ((lane & size) != 0);
        #pragma unroll
        for (int stride = size >> 1; stride > 0; stride >>= 1)
            cmpx(k, n, lane, stride, up);
    }
    #pragma unroll
    for (int stride = 32; stride > 0; stride >>= 1)   // final size-64 pass
        cmpx(k, n, lane, stride, asc);
}

// ---- Kernel 1: selection + grouped_xyz; sel indices -> d_ws (ushort) ----
// NOTE (R16 lesson): do NOT hand-roll ballot-aggregated LDS appends here —
// the compiler already wave-coalesces per-lane atomicAdd (one atomic/wave);
// the manual ballot ran unconditionally and cost +13 us.
__global__ __launch_bounds__(256, 8) void select_kernel(
    const float* __restrict__ radius_p,
    const float* __restrict__ hmin_p,
    const float* __restrict__ hmax_p,
    const float* __restrict__ xyz,      // (B, N, 3)
    const float* __restrict__ new_xyz,  // (B, P, 3)
    const float* __restrict__ rot,      // (B, P, 3, 3)
    float* __restrict__ out,            // (B, 3+C, P, S)
    unsigned short* __restrict__ selw)  // (B*P, 32)
{
    const int N = 16384, P = 1024, S = 32, OC = 67;
    const int bp  = blockIdx.x;
    const int b   = bp >> 10;          // P = 1024
    const int p   = bp & (P - 1);
    const int tid = threadIdx.x;
    const int lane = tid & 63;
    const int wv   = tid >> 6;

    __shared__ unsigned short cn[CAP]; // loose candidates (ushort: N fits 16b)
    __shared__ double wr2[256];        // per-wave sorted keys for the merge
    __shared__ int    wn[256];
    __shared__ int    cnt;             // loose count
    __shared__ int    cnt2;            // exact survivor count
    __shared__ int    sel[32];

    if (tid == 0) { cnt = 0; cnt2 = 0; }
    __syncthreads();

    const double radius = (double)radius_p[0];
    const double hmin   = (double)hmin_p[0];
    const double hmax   = (double)hmax_p[0];
    const double rad2   = radius * radius;

    const float* nx = new_xyz + (size_t)bp * 3;
    const double cx = nx[0], cy = nx[1], cz = nx[2];
    const float* rp = rot + (size_t)bp * 9;
    const double r00 = rp[0], r01 = rp[1], r02 = rp[2];
    const double r10 = rp[3], r11 = rp[4], r12 = rp[5];
    const double r20 = rp[6], r21 = rp[7], r22 = rp[8];

    // Projection-form f32 loose filter: local_d = P.u_d - cp_d where
    // cp_d = c.u_d is folded into one constant per output dim -> no per-point
    // subtractions. Error: abs err <= ~1e-5, 50-100x under the margins.
    const float r00f = (float)r00, r01f = (float)r01, r02f = (float)r02;
    const float r10f = (float)r10, r11f = (float)r11, r12f = (float)r12;
    const float r20f = (float)r20, r21f = (float)r21, r22f = (float)r22;
    const float cpxf = (float)(cx * r00 + cy * r10 + cz * r20);
    const float cpyf = (float)(cx * r01 + cy * r11 + cz * r21);
    const float cpzf = (float)(cx * r02 + cy * r12 + cz * r22);
    const float hminf = (float)hmin - 5.0e-4f;
    const float hmaxf = (float)hmax + 5.0e-4f;
    const float rad2f = (float)rad2 + 1.0e-3f;

    const float* xb = xyz + (size_t)b * N * 3;
    const float4* vp = reinterpret_cast<const float4*>(xb);

    // ---- Phase 1: pure-f32 loose scan, software-pipelined loads ----
    float4 a0 = vp[tid * 3 + 0], a1 = vp[tid * 3 + 1], a2 = vp[tid * 3 + 2];
    for (int it = 0; it < 16; ++it) {               // 16 * 1024 = N
        const float4* q = vp + ((it + 1) & 15) * 768 + tid * 3;
        float4 b0 = q[0], b1 = q[1], b2 = q[2];     // prefetch (issue-early)
        int g = it * 1024 + tid * 4;
        float px[4], py[4], pz[4];
        px[0]=a0.x; py[0]=a0.y; pz[0]=a0.z;
        px[1]=a0.w; py[1]=a1.x; pz[1]=a1.y;
        px[2]=a1.z; py[2]=a1.w; pz[2]=a2.x;
        px[3]=a2.y; py[3]=a2.z; pz[3]=a2.w;
        #pragma unroll
        for (int k = 0; k < 4; ++k) {
            float xf  = fmaf(px[k], r00f, fmaf(py[k], r10f, fmaf(pz[k], r20f, -cpxf)));
            float yf  = fmaf(px[k], r01f, fmaf(py[k], r11f, fmaf(pz[k], r21f, -cpyf)));
            float zf  = fmaf(px[k], r02f, fmaf(py[k], r12f, fmaf(pz[k], r22f, -cpzf)));
            float r2f = fmaf(yf, yf, zf * zf);
            if (xf >= hminf && xf <= hmaxf && r2f < rad2f) {
                int slot = atomicAdd(&cnt, 1);
                if (slot < CAP) cn[slot] = (unsigned short)(g + k);
            }
        }
        a0 = b0; a1 = b1; a2 = b2;
    }
    __syncthreads();

    // Overflow-proof: if loose set overflowed, scan ALL points in phase 2.
    int  Mloose = cnt;
    bool ident  = false;
    if (Mloose > CAP) { Mloose = N; ident = true; }

    // ---- Phase 2: exact f64 decision fused into chunk load + streaming
    //      bitonic top-64 per wave, then 4-way merge ----
    // Exact decision (same op order as verified R1-R15) once per candidate,
    // dense 64-wide chunks; rejects = BIGK sentinels; survivor count via
    // ballot popcount.
    double rk = BIGK; int rn = IDXINF;
    int msum = 0;
    const int nch = (Mloose + 63) >> 6;
    for (int ch = wv; ch < nch; ch += 4) {
        int j = (ch << 6) + lane;
        double ck = BIGK; int cnn = IDXINF;
        bool ok = false;
        if (j < Mloose) {
            int n = ident ? j : (int)cn[j];
            double dx = (double)xb[n * 3 + 0] - cx;
            double dy = (double)xb[n * 3 + 1] - cy;
            double dz = (double)xb[n * 3 + 2] - cz;
            double x = dx * r00 + dy * r10 + dz * r20;
            double y = dx * r01 + dy * r11 + dz * r21;
            double z = dx * r02 + dy * r12 + dz * r22;
            double r2 = y * y + z * z;
            if (x >= hmin && x <= hmax && r2 < rad2) { ok = true; ck = r2; cnn = n; }
        }
        msum += __popcll(__ballot(ok));             // wave-uniform count
        wave_sort64(ck, cnn, lane, false);          // chunk descending
        if ((ck < rk) || (ck == rk && cnn < rn)) { rk = ck; rn = cnn; }  // keep 64 smallest
        #pragma unroll
        for (int stride = 32; stride > 0; stride >>= 1)  // bitonic clean -> ascending
            cmpx(rk, rn, lane, stride, true);
    }
    if (lane == 0 && msum > 0) atomicAdd(&cnt2, msum);
    // park each wave's sorted list for the cross-wave merge
    wr2[(wv << 6) + lane] = rk;
    wn [(wv << 6) + lane] = rn;
    __syncthreads();

    if (wv == 0) {
        const int Mtrue = cnt2;
        #pragma unroll
        for (int w = 1; w < 4; ++w) {
            int src = (w << 6) + (63 - lane);       // reversed -> descending
            double ck = wr2[src]; int cnn = wn[src];
            if ((ck < rk) || (ck == rk && cnn < rn)) { rk = ck; rn = cnn; }
            #pragma unroll
            for (int stride = 32; stride > 0; stride >>= 1)
                cmpx(rk, rn, lane, stride, true);
        }
        // lanes 0..31 now hold the exact top-32 in ascending (r2, idx) order
        int nsel  = min(Mtrue, S);
        int first = __shfl(rn, 0);
        int v = (lane < nsel) ? rn : ((nsel > 0) ? first : 0);
        if (lane < S) sel[lane] = v;
    }
    __syncthreads();

    // ---- grouped_xyz + sel store ----
    if (tid < S) {
        int n = sel[tid];
        selw[(size_t)bp * S + tid] = (unsigned short)n;
        double dx = (double)xb[n * 3 + 0] - cx;
        double dy = (double)xb[n * 3 + 1] - cy;
        double dz = (double)xb[n * 3 + 2] - cz;
        float x = (float)(dx * r00 + dy * r10 + dz * r20);
        float y = (float)(dx * r01 + dy * r11 + dz * r21);
        float z = (float)(dx * r02 + dy * r12 + dz * r22);
        float* o = out + (((size_t)b * OC + 0) * P + p) * S + tid;
        o[0 * (size_t)P * S] = x;
        o[1 * (size_t)P * S] = y;
        o[2 * (size_t)P * S] = z;
    }
}

// ---- Kernel 2: transposed feature gather, one feat row per block ----
// (R16-verified fast version) grid 512, block 1024: c = bid & 63,
// half = (bid>>6) & 1, b = bid >> 7. Each thread: 16 INDEPENDENT gathers
// (load-all-then-store-all -> 16 outstanding loads of memory-level
// parallelism). Nontemporal stores keep the 33.5 MB output stream from
// evicting the L2-hot feat rows.
__global__ __launch_bounds__(1024, 8) void gather_kernel(
    const float* __restrict__ feat,           // (B, C, N)
    const unsigned short* __restrict__ selw,  // (B*P, 32)
    float* __restrict__ out)                  // (B, 3+C, P, S)
{
    const int N = 16384, P = 1024, C = 64, S = 32, OC = 67;
    const int bid  = blockIdx.x;
    const int c    = bid & 63;
    const int half = (bid >> 6) & 1;
    const int b    = bid >> 7;
    const int tid  = threadIdx.x;

    __shared__ unsigned short st[512 * 32];   // 32 KB sel tile (512 queries)

    const uint4* sp = reinterpret_cast<const uint4*>(
        selw + ((size_t)b * P + half * 512) * S);
    uint4* dl = reinterpret_cast<uint4*>(st);
    dl[tid]        = sp[tid];                 // 2048 uint4 / 1024 thr
    dl[1024 + tid] = sp[1024 + tid];
    __syncthreads();

    const float* fr = feat + ((size_t)b * C + c) * N;
    float* ob = out + (((size_t)b * OC + 3 + c) * P + half * 512) * S;

    int   ix[16];
    float v [16];
    #pragma unroll
    for (int k = 0; k < 16; ++k)              // LDS reads (cheap)
        ix[k] = st[k * 1024 + tid];
    #pragma unroll
    for (int k = 0; k < 16; ++k)              // 16 outstanding global loads
        v[k] = fr[ix[k]];
    #pragma unroll
    for (int k = 0; k < 16; ++k)              // coalesced streaming stores
        __builtin_nontemporal_store(v[k], &ob[k * 1024 + tid]);
}

extern "C" void kernel_launch(void* const* d_in, const int* in_sizes, int n_in,
                              void* d_out, int out_size, void* d_ws, size_t ws_size,
                              hipStream_t stream) {
    const float* radius  = (const float*)d_in[0];
    const float* hmin    = (const float*)d_in[1];
    const float* hmax    = (const float*)d_in[2];
    // d_in[3] = nsample (int, fixed 32) — compile-time constant here
    const float* xyz     = (const float*)d_in[4];
    const float* new_xyz = (const float*)d_in[5];
    const float* rot     = (const float*)d_in[6];
    const float* feat    = (const float*)d_in[7];
    float* out = (float*)d_out;
    unsigned short* selw = (unsigned short*)d_ws;   // 4096*32*2 = 256 KB

    hipLaunchKernelGGL(select_kernel, dim3(4096), dim3(256), 0, stream,
                       radius, hmin, hmax, xyz, new_xyz, rot, out, selw);
    hipLaunchKernelGGL(gather_kernel, dim3(512), dim3(1024), 0, stream,
                       feat, selw, out);
}